// Round 4
// baseline (20607.388 us; speedup 1.0000x reference)
//
#include <hip/hip_runtime.h>

typedef unsigned short u16;
typedef unsigned int   u32;
typedef __bf16 bf16x8 __attribute__((ext_vector_type(8)));
typedef float  f32x4  __attribute__((ext_vector_type(4)));
static_assert(sizeof(bf16x8) == 16, "bf16x8 size");

#define NL   219
#define NOUT 191

__device__ const int LAGS[6] = {1, 2, 3, 7, 14, 28};

// ---- workspace layout (byte offsets). Packed weights in MFMA B-fragment order.
#define OFF_P0H 0UL
#define OFF_P0L (OFF_P0H + 2097152UL)   // cell0 pack: 128 ntile * 16 kb * 512 u16
#define OFF_P1H (OFF_P0L + 2097152UL)   // cell1 pack hi: 128 * 32 * 512 u16
#define OFF_P1L (OFF_P1H + 4194304UL)
#define OFF_H1H (OFF_P1L + 4194304UL)   // [2 parity][512*512] u16
#define OFF_H1L (OFF_H1H + 1048576UL)
#define OFF_H2H (OFF_H1L + 1048576UL)
#define OFF_H2L (OFF_H2H + 1048576UL)
#define OFF_H2F (OFF_H2L + 1048576UL)   // [2][512*512] f32
#define OFF_XF  (OFF_H2F + 2097152UL)   // encoder features [168][512][10] f32
#define OFF_SC  (OFF_XF  + 3440640UL)
#define OFF_LS  (OFF_SC  + 2048UL)
#define OFF_VAL (OFF_LS  + 2048UL)      // scaled series vals [512][52] f32
#define OFF_BAR (OFF_VAL + 106496UL)    // grid barrier state
#define WS_NEED (OFF_BAR + 64UL)
#define HPAR 262144UL                   // elements per parity plane

__device__ __forceinline__ float sigm(float x){ return 1.f / (1.f + __expf(-x)); }
__device__ __forceinline__ float tanhx(float x){
  float ax = fabsf(x);
  float t  = __expf(-2.f * ax);
  float r  = (1.f - t) / (1.f + t);
  return copysignf(r, x);
}
__device__ __forceinline__ u16 f2bf(float x){
  u32 u = __float_as_uint(x);
  return (u16)((u + 0x7FFFu + ((u >> 16) & 1u)) >> 16);  // RNE
}
__device__ __forceinline__ float bf2f(u16 h){ return __uint_as_float(((u32)h) << 16); }

// Hang-proof grid barrier: monotonic generation + per-block register target.
// Stale generation reads can only cause extra spinning, never early exit.
// Bounded spin (~20ms) turns any structural failure into a wrong answer, not a hang.
__device__ __forceinline__ void gridbar(u32* bar, u32 target){
  __syncthreads();
  if (threadIdx.x == 0){
    __threadfence();
    u32 a = __hip_atomic_fetch_add(bar, 1u, __ATOMIC_ACQ_REL, __HIP_MEMORY_SCOPE_AGENT);
    if (a == 255u){
      __hip_atomic_store(bar, 0u, __ATOMIC_RELAXED, __HIP_MEMORY_SCOPE_AGENT);
      __hip_atomic_fetch_add(bar + 1, 1u, __ATOMIC_RELEASE, __HIP_MEMORY_SCOPE_AGENT);
    } else {
      u32 sp = 0;
      while (__hip_atomic_load(bar + 1, __ATOMIC_ACQUIRE, __HIP_MEMORY_SCOPE_AGENT) < target
             && ++sp < (1u << 17))
        __builtin_amdgcn_s_sleep(2);
    }
    __threadfence();
  }
  __syncthreads();
}

// Gate GEMM tile, MF=2 (wave covers 32 rows x 64 gate-cols), K=32*KB, 3-term bf16 split.
// B-hi from LDS (bh_s), B-lo from bl_s (LDS for cell0, global for cell1).
// A (h state) from global parity planes; KB=32 splits A across h1 (kb<16) and h2 (kb>=16).
template<int KB>
__device__ __forceinline__ void cell_mfma2(
    const u16* __restrict__ AhiA, const u16* __restrict__ AloA,
    const u16* __restrict__ AhiB, const u16* __restrict__ AloB,
    const u16* bh_s, const u16* bl_s,
    int R0, float4 bias4, f32x4 (&acc)[2][4])
{
  const int lane = threadIdx.x & 63;
  const int lrow = lane & 15;
  {
    const float* bp = (const float*)&bias4;
    #pragma unroll
    for (int nf = 0; nf < 4; nf++){
      float bv = bp[nf];
      f32x4 v = {bv, bv, bv, bv};
      acc[0][nf] = v; acc[1][nf] = v;
    }
  }
  const size_t alo = (size_t)(lane >> 4) * 8;
  const u32 bo0 = (u32)lane * 8;
  #pragma unroll 4
  for (int kb = 0; kb < KB; kb++){
    const u16* Ah; const u16* Al; int kl;
    if (KB == 16 || kb < 16){ Ah = AhiA; Al = AloA; kl = kb; }
    else                     { Ah = AhiB; Al = AloB; kl = kb - 16; }
    bf16x8 ah[2], al[2];
    #pragma unroll
    for (int mf = 0; mf < 2; mf++){
      size_t ao = (size_t)(R0 + mf * 16 + lrow) * 512 + (size_t)kl * 32 + alo;
      ah[mf] = *(const bf16x8*)(Ah + ao);
      al[mf] = *(const bf16x8*)(Al + ao);
    }
    bf16x8 bh[4], bl[4];
    #pragma unroll
    for (int nf = 0; nf < 4; nf++){
      u32 off = ((u32)(nf * KB + kb) << 9) + bo0;
      bh[nf] = *(const bf16x8*)(bh_s + off);
      bl[nf] = *(const bf16x8*)(bl_s + off);
    }
    #pragma unroll
    for (int mf = 0; mf < 2; mf++){
      #pragma unroll
      for (int nf = 0; nf < 4; nf++){
        acc[mf][nf] = __builtin_amdgcn_mfma_f32_16x16x32_bf16(ah[mf], bh[nf], acc[mf][nf], 0, 0, 0);
        acc[mf][nf] = __builtin_amdgcn_mfma_f32_16x16x32_bf16(ah[mf], bl[nf], acc[mf][nf], 0, 0, 0);
        acc[mf][nf] = __builtin_amdgcn_mfma_f32_16x16x32_bf16(al[mf], bh[nf], acc[mf][nf], 0, 0, 0);
      }
    }
  }
}

// pointwise LSTM update; c-state held in registers across all 191 steps.
template<bool XP>
__device__ __forceinline__ void cell_epi2(
    f32x4 (&acc)[2][4], float (&creg)[8], int wrowbase, int m0, int jt,
    const float* xSl, const float* WihSl,
    u16* __restrict__ hhd, u16* __restrict__ hld, float* __restrict__ hfd)
{
  const int lane = threadIdx.x & 63;
  const int lrow = lane & 15, lkb = lane >> 4;
  const int j = jt * 16 + lrow;
  #pragma unroll
  for (int mf = 0; mf < 2; mf++){
    #pragma unroll
    for (int r = 0; r < 4; r++){
      int lr = wrowbase + mf * 16 + lkb * 4 + r;
      int b  = m0 + lr;
      float gi = acc[mf][0][r], gf = acc[mf][1][r], gg = acc[mf][2][r], go = acc[mf][3][r];
      if (XP){
        #pragma unroll
        for (int k = 0; k < 10; k++){
          float xv = xSl[lr * 10 + k];
          gi += xv * WihSl[(0 * 16 + lrow) * 10 + k];
          gf += xv * WihSl[(1 * 16 + lrow) * 10 + k];
          gg += xv * WihSl[(2 * 16 + lrow) * 10 + k];
          go += xv * WihSl[(3 * 16 + lrow) * 10 + k];
        }
      }
      float co = creg[mf * 4 + r];
      float cn = sigm(gf) * co + sigm(gi) * tanhx(gg);
      float h  = sigm(go) * tanhx(cn);
      creg[mf * 4 + r] = cn;
      size_t ci = ((size_t)b << 9) + j;
      u16 hh = f2bf(h);
      hhd[ci] = hh;
      hld[ci] = f2bf(h - bf2f(hh));
      if (hfd) hfd[ci] = h;
    }
  }
}

__global__ void initbar(unsigned char* ws){
  if (threadIdx.x < 16) ((u32*)(ws + OFF_BAR))[threadIdx.x] = 0;
}

__global__ __launch_bounds__(256, 1) void deepar(
    const float* __restrict__ X,    const float* __restrict__ Wih0,
    const float* __restrict__ Whh0, const float* __restrict__ b0,
    const float* __restrict__ Wih1, const float* __restrict__ Whh1,
    const float* __restrict__ b1,   const float* __restrict__ Whead,
    const float* __restrict__ bhead, float* __restrict__ out,
    unsigned char* ws)
{
  __shared__ u16   BW[65536];     // 128 KB weight slice (cell0: hi+lo; cell1: hi)
  __shared__ float xS[1280];      // x features [128 rows][10]
  __shared__ float WihS[640];     // W_ih0 slice [64 gate-cols][10]
  __shared__ float WhS[512];      // W_head
  __shared__ float ylds[128];
  __shared__ float redS[4];

  u16*  p0h = (u16*)(ws + OFF_P0H);
  u16*  p0l = (u16*)(ws + OFF_P0L);
  u16*  p1h = (u16*)(ws + OFF_P1H);
  u16*  p1l = (u16*)(ws + OFF_P1L);
  u16*  h1h = (u16*)(ws + OFF_H1H);
  u16*  h1l = (u16*)(ws + OFF_H1L);
  u16*  h2h = (u16*)(ws + OFF_H2H);
  u16*  h2l = (u16*)(ws + OFF_H2L);
  float* h2f = (float*)(ws + OFF_H2F);
  float* xf  = (float*)(ws + OFF_XF);
  float* scp = (float*)(ws + OFF_SC);
  float* lsp = (float*)(ws + OFF_LS);
  float* valp = (float*)(ws + OFF_VAL);
  u32*  bar = (u32*)(ws + OFF_BAR);

  const int tid  = threadIdx.x;
  const int w    = blockIdx.x;
  const int wave = tid >> 6;
  const int jt   = w & 31;
  const int m0   = ((w >> 5) & 3) * 128;
  const int G    = 65536;
  const int gtid = w * 256 + tid;
  u32 bcnt = 0;

  float creg[8];
  #pragma unroll
  for (int i = 0; i < 8; i++) creg[i] = 0.f;

  // preload bias (this block's 64 gate-cols) and head bias into registers
  float4 bias4;
  {
    const float* bb = (w < 128) ? b0 : b1;
    int c = jt * 16 + (tid & 15);
    bias4.x = bb[0 * 512 + c]; bias4.y = bb[1 * 512 + c];
    bias4.z = bb[2 * 512 + c]; bias4.w = bb[3 * 512 + c];
  }
  const float bheadv = bhead[0];

  // ================= prep-A: zero state, per-series scale, weight packing =================
  for (int i = gtid; i < 524288; i += G){ h1h[i] = 0; h1l[i] = 0; h2h[i] = 0; h2l[i] = 0; h2f[i] = 0.f; }
  {
    int rowb = w * 2 + (tid >> 7);
    int t0 = tid & 127;
    float a = fabsf(X[((size_t)rowb * NL + 28 + t0) * 3]);
    if (t0 < 40) a += fabsf(X[((size_t)rowb * NL + 156 + t0) * 3]);
    #pragma unroll
    for (int off = 1; off < 64; off <<= 1) a += __shfl_xor(a, off, 64);
    if ((tid & 63) == 0) redS[tid >> 6] = a;
    __syncthreads();
    if (tid == 0 || tid == 128){
      float s = redS[tid >> 6] + redS[(tid >> 6) + 1];
      float sc = fmaxf(s / 168.f, 0.001f);
      scp[rowb] = sc; lsp[rowb] = logf(sc);
    }
  }
  // pack cell0 B (W_hh0)
  for (int idx = gtid; idx < 1048576; idx += G){
    int e = idx & 7, ln = (idx >> 3) & 63, kb = (idx >> 9) & 15, nt = idx >> 13;
    int n = (nt & 3) * 512 + (nt >> 2) * 16 + (ln & 15);
    int k = kb * 32 + (ln >> 4) * 8 + e;
    float wv = Whh0[(size_t)n * 512 + k];
    u16 hh = f2bf(wv);
    p0h[idx] = hh; p0l[idx] = f2bf(wv - bf2f(hh));
  }
  // pack cell1 B ([W_ih1 ; W_hh1], K=1024)
  for (int idx = gtid; idx < 2097152; idx += G){
    int e = idx & 7, ln = (idx >> 3) & 63, kb = (idx >> 9) & 31, nt = idx >> 14;
    int n = (nt & 3) * 512 + (nt >> 2) * 16 + (ln & 15);
    int k = kb * 32 + (ln >> 4) * 8 + e;
    float wv = (k < 512) ? Wih1[(size_t)n * 512 + k] : Whh1[(size_t)n * 512 + (k - 512)];
    u16 hh = f2bf(wv);
    p1h[idx] = hh; p1l[idx] = f2bf(wv - bf2f(hh));
  }
  gridbar(bar, ++bcnt);

  // ================= prep-B: features, valp, LDS residents =================
  for (int idx = gtid; idx < 860160; idx += G){
    int k = idx % 10; int r = idx / 10; int b = r & 511; int t = r >> 9;
    size_t xb = (size_t)b * NL;
    float v;
    if (k == 0)      v = X[(xb + 28 + t) * 3] / scp[b];
    else if (k < 3)  v = X[(xb + 28 + t) * 3 + k];
    else if (k == 3) v = lsp[b];
    else { int lag = LAGS[k - 4]; v = X[(xb + 28 + t - lag) * 3] / scp[b]; }
    xf[idx] = v;
  }
  for (int idx = gtid; idx < 512 * 28; idx += G){
    int b = idx / 28, v = idx % 28;
    valp[b * 52 + v] = X[((size_t)b * NL + 168 + v) * 3] / scp[b];
  }
  // stage this block's weight slice into LDS (written by prep-A, after barrier)
  if (w < 128){
    const uint4* sh = (const uint4*)(p0h + (size_t)jt * 32768);
    const uint4* sl = (const uint4*)(p0l + (size_t)jt * 32768);
    uint4* dB = (uint4*)BW;
    for (int i = tid; i < 4096; i += 256){ dB[i] = sh[i]; dB[4096 + i] = sl[i]; }
    for (int i = tid; i < 640; i += 256){
      int col = i / 10, k = i % 10;
      int n = (col >> 4) * 512 + jt * 16 + (col & 15);
      WihS[i] = Wih0[n * 10 + k];
    }
    for (int i = tid; i < 512; i += 256) WhS[i] = Whead[i];
  } else {
    const uint4* sh = (const uint4*)(p1h + (size_t)jt * 65536);
    uint4* dB = (uint4*)BW;
    for (int i = tid; i < 8192; i += 256) dB[i] = sh[i];
  }
  gridbar(bar, ++bcnt);

  // ================= encoder: pipelined, 1 barrier/phase =================
  // phase p: blocks 0-127 cell0(t=p); blocks 128-255 cell1(t=p-1); head y(t=p-2).
  for (int p = 0; p <= 168; p++){
    const int P = p & 1;
    if (w < 128){
      if ((w & 31) == 0 && p >= 2){
        int t = p - 2;
        int row = tid >> 1, q = tid & 1;
        int b = m0 + row;
        const float4* h4 = (const float4*)(h2f + (size_t)P * HPAR + ((size_t)b << 9) + q * 256);
        const float4* w4 = (const float4*)(WhS + q * 256);
        float s = 0.f;
        #pragma unroll 8
        for (int i = 0; i < 64; i++){ float4 a = h4[i], bw = w4[i]; s += a.x*bw.x + a.y*bw.y + a.z*bw.z + a.w*bw.w; }
        s += __shfl_xor(s, 1, 64);
        if (q == 0) out[(size_t)b * NOUT + t] = (s + bheadv) * scp[b];
      }
      if (p <= 167){
        for (int i = tid; i < 1280; i += 256) xS[i] = xf[(size_t)(p * 512 + m0) * 10 + i];
        __syncthreads();
        f32x4 acc[2][4];
        cell_mfma2<16>(h1h + (size_t)(1 - P) * HPAR, h1l + (size_t)(1 - P) * HPAR, nullptr, nullptr,
                       BW, BW + 32768, m0 + wave * 32, bias4, acc);
        cell_epi2<true>(acc, creg, wave * 32, m0, jt, xS, WihS,
                        h1h + (size_t)P * HPAR, h1l + (size_t)P * HPAR, nullptr);
      }
    } else {
      if (p >= 1){
        f32x4 acc[2][4];
        cell_mfma2<32>(h1h + (size_t)(1 - P) * HPAR, h1l + (size_t)(1 - P) * HPAR,
                       h2h + (size_t)P * HPAR,       h2l + (size_t)P * HPAR,
                       BW, p1l + (size_t)jt * 65536, m0 + wave * 32, bias4, acc);
        cell_epi2<false>(acc, creg, wave * 32, m0, jt, nullptr, nullptr,
                         h2h + (size_t)(1 - P) * HPAR, h2l + (size_t)(1 - P) * HPAR,
                         h2f + (size_t)(1 - P) * HPAR);
      }
    }
    gridbar(bar, ++bcnt);
  }

  // ================= decoder: 2 barriers/step =================
  for (int d = 0; d <= 22; d++){
    const int hp = (d + 1) & 1;     // parity of last h1/h2/h2f write
    if (w < 128){
      { // head y (output col 167+d); every cell0 block computes its own 128 rows
        int row = tid >> 1, q = tid & 1;
        int b = m0 + row;
        const float4* h4 = (const float4*)(h2f + (size_t)hp * HPAR + ((size_t)b << 9) + q * 256);
        const float4* w4 = (const float4*)(WhS + q * 256);
        float s = 0.f;
        #pragma unroll 8
        for (int i = 0; i < 64; i++){ float4 a = h4[i], bw = w4[i]; s += a.x*bw.x + a.y*bw.y + a.z*bw.z + a.w*bw.w; }
        s += __shfl_xor(s, 1, 64);
        if (q == 0){
          float y = s + bheadv;
          ylds[row] = y;
          if (jt == 0){
            out[(size_t)b * NOUT + 167 + d] = y * scp[b];
            valp[b * 52 + 28 + d] = y;
          }
        }
      }
      __syncthreads();
      if (tid < 128){
        int b = m0 + tid;
        size_t xb = (size_t)b * NL;
        float* xr = xS + tid * 10;
        xr[0] = ylds[tid];
        xr[1] = X[(xb + 196 + d) * 3 + 1];
        xr[2] = X[(xb + 196 + d) * 3 + 2];
        xr[3] = lsp[b];
        #pragma unroll
        for (int j2 = 0; j2 < 6; j2++) xr[4 + j2] = valp[b * 52 + 28 + d - LAGS[j2]];
      }
      __syncthreads();
      f32x4 acc[2][4];
      cell_mfma2<16>(h1h + (size_t)hp * HPAR, h1l + (size_t)hp * HPAR, nullptr, nullptr,
                     BW, BW + 32768, m0 + wave * 32, bias4, acc);
      cell_epi2<true>(acc, creg, wave * 32, m0, jt, xS, WihS,
                      h1h + (size_t)(d & 1) * HPAR, h1l + (size_t)(d & 1) * HPAR, nullptr);
    }
    gridbar(bar, ++bcnt);
    if (w >= 128){
      f32x4 acc[2][4];
      cell_mfma2<32>(h1h + (size_t)(d & 1) * HPAR, h1l + (size_t)(d & 1) * HPAR,
                     h2h + (size_t)hp * HPAR,      h2l + (size_t)hp * HPAR,
                     BW, p1l + (size_t)jt * 65536, m0 + wave * 32, bias4, acc);
      cell_epi2<false>(acc, creg, wave * 32, m0, jt, nullptr, nullptr,
                       h2h + (size_t)(d & 1) * HPAR, h2l + (size_t)(d & 1) * HPAR,
                       h2f + (size_t)(d & 1) * HPAR);
    }
    gridbar(bar, ++bcnt);
  }

  // final head: decoder step 23 output -> col 190 (h2f parity (22&1)=0)
  if (w < 128){
    int row = tid >> 1, q = tid & 1;
    int b = m0 + row;
    const float4* h4 = (const float4*)(h2f + ((size_t)b << 9) + q * 256);
    const float4* w4 = (const float4*)(WhS + q * 256);
    float s = 0.f;
    #pragma unroll 8
    for (int i = 0; i < 64; i++){ float4 a = h4[i], bw = w4[i]; s += a.x*bw.x + a.y*bw.y + a.z*bw.z + a.w*bw.w; }
    s += __shfl_xor(s, 1, 64);
    if (q == 0 && jt == 0) out[(size_t)b * NOUT + 190] = (s + bheadv) * scp[b];
  }
}

extern "C" void kernel_launch(void* const* d_in, const int* in_sizes, int n_in,
                              void* d_out, int out_size, void* d_ws, size_t ws_size,
                              hipStream_t stream) {
  (void)in_sizes; (void)n_in; (void)out_size;
  if (ws_size < WS_NEED) return;  // fail loudly (absmax) rather than corrupt
  const float* X    = (const float*)d_in[0];
  const float* Wih0 = (const float*)d_in[4];
  const float* Whh0 = (const float*)d_in[5];
  const float* b0   = (const float*)d_in[6];
  const float* Wih1 = (const float*)d_in[7];
  const float* Whh1 = (const float*)d_in[8];
  const float* b1   = (const float*)d_in[9];
  const float* Wh   = (const float*)d_in[10];
  const float* bh   = (const float*)d_in[11];
  float* out = (float*)d_out;
  unsigned char* ws = (unsigned char*)d_ws;

  initbar<<<dim3(1), dim3(64), 0, stream>>>(ws);
  deepar<<<dim3(256), dim3(256), 0, stream>>>(X, Wih0, Whh0, b0, Wih1, Whh1, b1, Wh, bh, out, ws);
}

// Round 7
// 9821.265 us; speedup vs baseline: 2.0982x; 2.0982x over previous
//
#include <hip/hip_runtime.h>

typedef unsigned short u16;
typedef unsigned int   u32;
typedef __bf16 bf16x8 __attribute__((ext_vector_type(8)));
typedef float  f32x4  __attribute__((ext_vector_type(4)));
static_assert(sizeof(bf16x8) == 16, "bf16x8 size");

#define NL   219
#define NOUT 191

__device__ const int LAGS[6] = {1, 2, 3, 7, 14, 28};

// ---- workspace layout (byte offsets). Packed weights in MFMA B-fragment order.
#define OFF_P0H 0UL
#define OFF_P0L (OFF_P0H + 2097152UL)   // cell0 pack: 128 ntile * 16 kb * 512 u16
#define OFF_P1H (OFF_P0L + 2097152UL)   // cell1 pack hi: 128 * 32 * 512 u16
#define OFF_P1L (OFF_P1H + 4194304UL)
#define OFF_H1H (OFF_P1L + 4194304UL)   // [2 parity][512*512] u16
#define OFF_H1L (OFF_H1H + 1048576UL)
#define OFF_H2H (OFF_H1L + 1048576UL)
#define OFF_H2L (OFF_H2H + 1048576UL)
#define OFF_H2F (OFF_H2L + 1048576UL)   // [2][512*512] f32
#define OFF_XF  (OFF_H2F + 2097152UL)   // encoder features [168][512][10] f32
#define OFF_SC  (OFF_XF  + 3440640UL)
#define OFF_LS  (OFF_SC  + 2048UL)
#define OFF_VAL (OFF_LS  + 2048UL)      // scaled series vals [512][52] f32
#define OFF_BAR (OFF_VAL + 106496UL)    // grid barrier state
#define WS_NEED (OFF_BAR + 64UL)
#define HPAR 262144UL                   // elements per parity plane

__device__ __forceinline__ float sigm(float x){ return 1.f / (1.f + __expf(-x)); }
__device__ __forceinline__ float tanhx(float x){
  float ax = fabsf(x);
  float t  = __expf(-2.f * ax);
  float r  = (1.f - t) / (1.f + t);
  return copysignf(r, x);
}
__device__ __forceinline__ u16 f2bf(float x){
  u32 u = __float_as_uint(x);
  return (u16)((u + 0x7FFFu + ((u >> 16) & 1u)) >> 16);  // RNE
}
__device__ __forceinline__ float bf2f(u16 h){ return __uint_as_float(((u32)h) << 16); }

// Grid barrier, cache-friendly edition.
// R4 post-mortem: ACQUIRE polling emitted buffer_inv per iteration -> continuous
// L1/L2 invalidation storm (95us/phase, 2.6GB FETCH). Now:
//   arrival  = fetch_add RELEASE   (publish h-writes, no invalidate)
//   poll     = RELAXED loads       (coherent-point read, no cache maintenance)
//   exit     = ONE acquire fence   (the single invalidation correctness needs)
// Monotone generation + per-block register target + bounded spin = hang-proof:
// stale reads only over-wait; structural failure -> wrong answer, never a hang.
__device__ __forceinline__ void gridbar(u32* bar, u32 target){
  __syncthreads();
  if (threadIdx.x == 0){
    u32 a = __hip_atomic_fetch_add(bar, 1u, __ATOMIC_RELEASE, __HIP_MEMORY_SCOPE_AGENT);
    if (a == 255u){
      __hip_atomic_store(bar, 0u, __ATOMIC_RELAXED, __HIP_MEMORY_SCOPE_AGENT);
      __hip_atomic_fetch_add(bar + 1, 1u, __ATOMIC_RELEASE, __HIP_MEMORY_SCOPE_AGENT);
    } else {
      u32 sp = 0;
      while (__hip_atomic_load(bar + 1, __ATOMIC_RELAXED, __HIP_MEMORY_SCOPE_AGENT) < target
             && ++sp < (1u << 17))
        __builtin_amdgcn_s_sleep(4);
    }
    __builtin_amdgcn_fence(__ATOMIC_ACQUIRE, "agent");
  }
  __syncthreads();
}

// Gate GEMM tile, MF=2 (wave covers 32 rows x 64 gate-cols), K=32*KB, 3-term bf16 split.
// B-hi from LDS (bh_s), B-lo from bl_s (LDS for cell0, global for cell1).
// A (h state) from global parity planes; KB=32 splits A across h1 (kb<16) and h2 (kb>=16).
template<int KB>
__device__ __forceinline__ void cell_mfma2(
    const u16* __restrict__ AhiA, const u16* __restrict__ AloA,
    const u16* __restrict__ AhiB, const u16* __restrict__ AloB,
    const u16* bh_s, const u16* bl_s,
    int R0, float4 bias4, f32x4 (&acc)[2][4])
{
  const int lane = threadIdx.x & 63;
  const int lrow = lane & 15;
  {
    const float* bp = (const float*)&bias4;
    #pragma unroll
    for (int nf = 0; nf < 4; nf++){
      float bv = bp[nf];
      f32x4 v = {bv, bv, bv, bv};
      acc[0][nf] = v; acc[1][nf] = v;
    }
  }
  const size_t alo = (size_t)(lane >> 4) * 8;
  const u32 bo0 = (u32)lane * 8;
  #pragma unroll 4
  for (int kb = 0; kb < KB; kb++){
    const u16* Ah; const u16* Al; int kl;
    if (KB == 16 || kb < 16){ Ah = AhiA; Al = AloA; kl = kb; }
    else                     { Ah = AhiB; Al = AloB; kl = kb - 16; }
    bf16x8 ah[2], al[2];
    #pragma unroll
    for (int mf = 0; mf < 2; mf++){
      size_t ao = (size_t)(R0 + mf * 16 + lrow) * 512 + (size_t)kl * 32 + alo;
      ah[mf] = *(const bf16x8*)(Ah + ao);
      al[mf] = *(const bf16x8*)(Al + ao);
    }
    bf16x8 bh[4], bl[4];
    #pragma unroll
    for (int nf = 0; nf < 4; nf++){
      u32 off = ((u32)(nf * KB + kb) << 9) + bo0;
      bh[nf] = *(const bf16x8*)(bh_s + off);
      bl[nf] = *(const bf16x8*)(bl_s + off);
    }
    #pragma unroll
    for (int mf = 0; mf < 2; mf++){
      #pragma unroll
      for (int nf = 0; nf < 4; nf++){
        acc[mf][nf] = __builtin_amdgcn_mfma_f32_16x16x32_bf16(ah[mf], bh[nf], acc[mf][nf], 0, 0, 0);
        acc[mf][nf] = __builtin_amdgcn_mfma_f32_16x16x32_bf16(ah[mf], bl[nf], acc[mf][nf], 0, 0, 0);
        acc[mf][nf] = __builtin_amdgcn_mfma_f32_16x16x32_bf16(al[mf], bh[nf], acc[mf][nf], 0, 0, 0);
      }
    }
  }
}

// pointwise LSTM update; c-state held in registers across all 191 steps.
template<bool XP>
__device__ __forceinline__ void cell_epi2(
    f32x4 (&acc)[2][4], float (&creg)[8], int wrowbase, int m0, int jt,
    const float* xSl, const float* WihSl,
    u16* __restrict__ hhd, u16* __restrict__ hld, float* __restrict__ hfd)
{
  const int lane = threadIdx.x & 63;
  const int lrow = lane & 15, lkb = lane >> 4;
  const int j = jt * 16 + lrow;
  #pragma unroll
  for (int mf = 0; mf < 2; mf++){
    #pragma unroll
    for (int r = 0; r < 4; r++){
      int lr = wrowbase + mf * 16 + lkb * 4 + r;
      int b  = m0 + lr;
      float gi = acc[mf][0][r], gf = acc[mf][1][r], gg = acc[mf][2][r], go = acc[mf][3][r];
      if (XP){
        #pragma unroll
        for (int k = 0; k < 10; k++){
          float xv = xSl[lr * 10 + k];
          gi += xv * WihSl[(0 * 16 + lrow) * 10 + k];
          gf += xv * WihSl[(1 * 16 + lrow) * 10 + k];
          gg += xv * WihSl[(2 * 16 + lrow) * 10 + k];
          go += xv * WihSl[(3 * 16 + lrow) * 10 + k];
        }
      }
      float co = creg[mf * 4 + r];
      float cn = sigm(gf) * co + sigm(gi) * tanhx(gg);
      float h  = sigm(go) * tanhx(cn);
      creg[mf * 4 + r] = cn;
      size_t ci = ((size_t)b << 9) + j;
      u16 hh = f2bf(h);
      hhd[ci] = hh;
      hld[ci] = f2bf(h - bf2f(hh));
      if (hfd) hfd[ci] = h;
    }
  }
}

__global__ void initbar(unsigned char* ws){
  if (threadIdx.x < 16) ((u32*)(ws + OFF_BAR))[threadIdx.x] = 0;
}

__global__ __launch_bounds__(256, 1) void deepar(
    const float* __restrict__ X,    const float* __restrict__ Wih0,
    const float* __restrict__ Whh0, const float* __restrict__ b0,
    const float* __restrict__ Wih1, const float* __restrict__ Whh1,
    const float* __restrict__ b1,   const float* __restrict__ Whead,
    const float* __restrict__ bhead, float* __restrict__ out,
    unsigned char* ws)
{
  __shared__ u16   BW[65536];     // 128 KB weight slice (cell0: hi+lo; cell1: hi)
  __shared__ float xS[1280];      // x features [128 rows][10]
  __shared__ float WihS[640];     // W_ih0 slice [64 gate-cols][10]
  __shared__ float WhS[512];      // W_head
  __shared__ float ylds[128];
  __shared__ float redS[4];

  u16*  p0h = (u16*)(ws + OFF_P0H);
  u16*  p0l = (u16*)(ws + OFF_P0L);
  u16*  p1h = (u16*)(ws + OFF_P1H);
  u16*  p1l = (u16*)(ws + OFF_P1L);
  u16*  h1h = (u16*)(ws + OFF_H1H);
  u16*  h1l = (u16*)(ws + OFF_H1L);
  u16*  h2h = (u16*)(ws + OFF_H2H);
  u16*  h2l = (u16*)(ws + OFF_H2L);
  float* h2f = (float*)(ws + OFF_H2F);
  float* xf  = (float*)(ws + OFF_XF);
  float* scp = (float*)(ws + OFF_SC);
  float* lsp = (float*)(ws + OFF_LS);
  float* valp = (float*)(ws + OFF_VAL);
  u32*  bar = (u32*)(ws + OFF_BAR);

  const int tid  = threadIdx.x;
  const int w    = blockIdx.x;
  const int wave = tid >> 6;
  const int jt   = w & 31;
  const int m0   = ((w >> 5) & 3) * 128;
  const int G    = 65536;
  const int gtid = w * 256 + tid;
  u32 bcnt = 0;

  float creg[8];
  #pragma unroll
  for (int i = 0; i < 8; i++) creg[i] = 0.f;

  // preload bias (this block's 64 gate-cols) and head bias into registers
  float4 bias4;
  {
    const float* bb = (w < 128) ? b0 : b1;
    int c = jt * 16 + (tid & 15);
    bias4.x = bb[0 * 512 + c]; bias4.y = bb[1 * 512 + c];
    bias4.z = bb[2 * 512 + c]; bias4.w = bb[3 * 512 + c];
  }
  const float bheadv = bhead[0];

  // ================= prep-A: zero state, per-series scale, weight packing =================
  for (int i = gtid; i < 524288; i += G){ h1h[i] = 0; h1l[i] = 0; h2h[i] = 0; h2l[i] = 0; h2f[i] = 0.f; }
  {
    int rowb = w * 2 + (tid >> 7);
    int t0 = tid & 127;
    float a = fabsf(X[((size_t)rowb * NL + 28 + t0) * 3]);
    if (t0 < 40) a += fabsf(X[((size_t)rowb * NL + 156 + t0) * 3]);
    #pragma unroll
    for (int off = 1; off < 64; off <<= 1) a += __shfl_xor(a, off, 64);
    if ((tid & 63) == 0) redS[tid >> 6] = a;
    __syncthreads();
    if (tid == 0 || tid == 128){
      float s = redS[tid >> 6] + redS[(tid >> 6) + 1];
      float sc = fmaxf(s / 168.f, 0.001f);
      scp[rowb] = sc; lsp[rowb] = logf(sc);
    }
  }
  // pack cell0 B (W_hh0)
  for (int idx = gtid; idx < 1048576; idx += G){
    int e = idx & 7, ln = (idx >> 3) & 63, kb = (idx >> 9) & 15, nt = idx >> 13;
    int n = (nt & 3) * 512 + (nt >> 2) * 16 + (ln & 15);
    int k = kb * 32 + (ln >> 4) * 8 + e;
    float wv = Whh0[(size_t)n * 512 + k];
    u16 hh = f2bf(wv);
    p0h[idx] = hh; p0l[idx] = f2bf(wv - bf2f(hh));
  }
  // pack cell1 B ([W_ih1 ; W_hh1], K=1024)
  for (int idx = gtid; idx < 2097152; idx += G){
    int e = idx & 7, ln = (idx >> 3) & 63, kb = (idx >> 9) & 31, nt = idx >> 14;
    int n = (nt & 3) * 512 + (nt >> 2) * 16 + (ln & 15);
    int k = kb * 32 + (ln >> 4) * 8 + e;
    float wv = (k < 512) ? Wih1[(size_t)n * 512 + k] : Whh1[(size_t)n * 512 + (k - 512)];
    u16 hh = f2bf(wv);
    p1h[idx] = hh; p1l[idx] = f2bf(wv - bf2f(hh));
  }
  gridbar(bar, ++bcnt);

  // ================= prep-B: features, valp, LDS residents =================
  for (int idx = gtid; idx < 860160; idx += G){
    int k = idx % 10; int r = idx / 10; int b = r & 511; int t = r >> 9;
    size_t xb = (size_t)b * NL;
    float v;
    if (k == 0)      v = X[(xb + 28 + t) * 3] / scp[b];
    else if (k < 3)  v = X[(xb + 28 + t) * 3 + k];
    else if (k == 3) v = lsp[b];
    else { int lag = LAGS[k - 4]; v = X[(xb + 28 + t - lag) * 3] / scp[b]; }
    xf[idx] = v;
  }
  for (int idx = gtid; idx < 512 * 28; idx += G){
    int b = idx / 28, v = idx % 28;
    valp[b * 52 + v] = X[((size_t)b * NL + 168 + v) * 3] / scp[b];
  }
  // stage this block's weight slice into LDS (written by prep-A, after barrier)
  if (w < 128){
    const uint4* sh = (const uint4*)(p0h + (size_t)jt * 32768);
    const uint4* sl = (const uint4*)(p0l + (size_t)jt * 32768);
    uint4* dB = (uint4*)BW;
    for (int i = tid; i < 4096; i += 256){ dB[i] = sh[i]; dB[4096 + i] = sl[i]; }
    for (int i = tid; i < 640; i += 256){
      int col = i / 10, k = i % 10;
      int n = (col >> 4) * 512 + jt * 16 + (col & 15);
      WihS[i] = Wih0[n * 10 + k];
    }
    for (int i = tid; i < 512; i += 256) WhS[i] = Whead[i];
  } else {
    const uint4* sh = (const uint4*)(p1h + (size_t)jt * 65536);
    uint4* dB = (uint4*)BW;
    for (int i = tid; i < 8192; i += 256) dB[i] = sh[i];
  }
  gridbar(bar, ++bcnt);

  // ================= encoder: pipelined, 1 barrier/phase =================
  // phase p: blocks 0-127 cell0(t=p); blocks 128-255 cell1(t=p-1); head y(t=p-2).
  for (int p = 0; p <= 168; p++){
    const int P = p & 1;
    if (w < 128){
      if ((w & 31) == 0 && p >= 2){
        int t = p - 2;
        int row = tid >> 1, q = tid & 1;
        int b = m0 + row;
        const float4* h4 = (const float4*)(h2f + (size_t)P * HPAR + ((size_t)b << 9) + q * 256);
        const float4* w4 = (const float4*)(WhS + q * 256);
        float s = 0.f;
        #pragma unroll 8
        for (int i = 0; i < 64; i++){ float4 a = h4[i], bw = w4[i]; s += a.x*bw.x + a.y*bw.y + a.z*bw.z + a.w*bw.w; }
        s += __shfl_xor(s, 1, 64);
        if (q == 0) out[(size_t)b * NOUT + t] = (s + bheadv) * scp[b];
      }
      if (p <= 167){
        for (int i = tid; i < 1280; i += 256) xS[i] = xf[(size_t)(p * 512 + m0) * 10 + i];
        __syncthreads();
        f32x4 acc[2][4];
        cell_mfma2<16>(h1h + (size_t)(1 - P) * HPAR, h1l + (size_t)(1 - P) * HPAR, nullptr, nullptr,
                       BW, BW + 32768, m0 + wave * 32, bias4, acc);
        cell_epi2<true>(acc, creg, wave * 32, m0, jt, xS, WihS,
                        h1h + (size_t)P * HPAR, h1l + (size_t)P * HPAR, nullptr);
      }
    } else {
      if (p >= 1){
        f32x4 acc[2][4];
        cell_mfma2<32>(h1h + (size_t)(1 - P) * HPAR, h1l + (size_t)(1 - P) * HPAR,
                       h2h + (size_t)P * HPAR,       h2l + (size_t)P * HPAR,
                       BW, p1l + (size_t)jt * 65536, m0 + wave * 32, bias4, acc);
        cell_epi2<false>(acc, creg, wave * 32, m0, jt, nullptr, nullptr,
                         h2h + (size_t)(1 - P) * HPAR, h2l + (size_t)(1 - P) * HPAR,
                         h2f + (size_t)(1 - P) * HPAR);
      }
    }
    gridbar(bar, ++bcnt);
  }

  // ================= decoder: 2 barriers/step =================
  for (int d = 0; d <= 22; d++){
    const int hp = (d + 1) & 1;     // parity of last h1/h2/h2f write
    if (w < 128){
      { // head y (output col 167+d); every cell0 block computes its own 128 rows
        int row = tid >> 1, q = tid & 1;
        int b = m0 + row;
        const float4* h4 = (const float4*)(h2f + (size_t)hp * HPAR + ((size_t)b << 9) + q * 256);
        const float4* w4 = (const float4*)(WhS + q * 256);
        float s = 0.f;
        #pragma unroll 8
        for (int i = 0; i < 64; i++){ float4 a = h4[i], bw = w4[i]; s += a.x*bw.x + a.y*bw.y + a.z*bw.z + a.w*bw.w; }
        s += __shfl_xor(s, 1, 64);
        if (q == 0){
          float y = s + bheadv;
          ylds[row] = y;
          if (jt == 0){
            out[(size_t)b * NOUT + 167 + d] = y * scp[b];
            valp[b * 52 + 28 + d] = y;
          }
        }
      }
      __syncthreads();
      if (tid < 128){
        int b = m0 + tid;
        size_t xb = (size_t)b * NL;
        float* xr = xS + tid * 10;
        xr[0] = ylds[tid];
        xr[1] = X[(xb + 196 + d) * 3 + 1];
        xr[2] = X[(xb + 196 + d) * 3 + 2];
        xr[3] = lsp[b];
        #pragma unroll
        for (int j2 = 0; j2 < 6; j2++) xr[4 + j2] = valp[b * 52 + 28 + d - LAGS[j2]];
      }
      __syncthreads();
      f32x4 acc[2][4];
      cell_mfma2<16>(h1h + (size_t)hp * HPAR, h1l + (size_t)hp * HPAR, nullptr, nullptr,
                     BW, BW + 32768, m0 + wave * 32, bias4, acc);
      cell_epi2<true>(acc, creg, wave * 32, m0, jt, xS, WihS,
                      h1h + (size_t)(d & 1) * HPAR, h1l + (size_t)(d & 1) * HPAR, nullptr);
    }
    gridbar(bar, ++bcnt);
    if (w >= 128){
      f32x4 acc[2][4];
      cell_mfma2<32>(h1h + (size_t)(d & 1) * HPAR, h1l + (size_t)(d & 1) * HPAR,
                     h2h + (size_t)hp * HPAR,      h2l + (size_t)hp * HPAR,
                     BW, p1l + (size_t)jt * 65536, m0 + wave * 32, bias4, acc);
      cell_epi2<false>(acc, creg, wave * 32, m0, jt, nullptr, nullptr,
                       h2h + (size_t)(d & 1) * HPAR, h2l + (size_t)(d & 1) * HPAR,
                       h2f + (size_t)(d & 1) * HPAR);
    }
    gridbar(bar, ++bcnt);
  }

  // final head: decoder step 23 output -> col 190 (h2f parity (22&1)=0)
  if (w < 128){
    int row = tid >> 1, q = tid & 1;
    int b = m0 + row;
    const float4* h4 = (const float4*)(h2f + ((size_t)b << 9) + q * 256);
    const float4* w4 = (const float4*)(WhS + q * 256);
    float s = 0.f;
    #pragma unroll 8
    for (int i = 0; i < 64; i++){ float4 a = h4[i], bw = w4[i]; s += a.x*bw.x + a.y*bw.y + a.z*bw.z + a.w*bw.w; }
    s += __shfl_xor(s, 1, 64);
    if (q == 0 && jt == 0) out[(size_t)b * NOUT + 190] = (s + bheadv) * scp[b];
  }
}

extern "C" void kernel_launch(void* const* d_in, const int* in_sizes, int n_in,
                              void* d_out, int out_size, void* d_ws, size_t ws_size,
                              hipStream_t stream) {
  (void)in_sizes; (void)n_in; (void)out_size;
  if (ws_size < WS_NEED) return;  // fail loudly (absmax) rather than corrupt
  const float* X    = (const float*)d_in[0];
  const float* Wih0 = (const float*)d_in[4];
  const float* Whh0 = (const float*)d_in[5];
  const float* b0   = (const float*)d_in[6];
  const float* Wih1 = (const float*)d_in[7];
  const float* Whh1 = (const float*)d_in[8];
  const float* b1   = (const float*)d_in[9];
  const float* Wh   = (const float*)d_in[10];
  const float* bh   = (const float*)d_in[11];
  float* out = (float*)d_out;
  unsigned char* ws = (unsigned char*)d_ws;

  initbar<<<dim3(1), dim3(64), 0, stream>>>(ws);
  deepar<<<dim3(256), dim3(256), 0, stream>>>(X, Wih0, Whh0, b0, Wih1, Whh1, b1, Wh, bh, out, ws);
}

// Round 8
// 8849.303 us; speedup vs baseline: 2.3287x; 1.1098x over previous
//
#include <hip/hip_runtime.h>

typedef unsigned short u16;
typedef unsigned int   u32;
typedef __bf16 bf16x8 __attribute__((ext_vector_type(8)));
typedef float  f32x4  __attribute__((ext_vector_type(4)));
static_assert(sizeof(bf16x8) == 16, "bf16x8 size");

#define NL   219
#define NOUT 191

__device__ const int LAGS[6] = {1, 2, 3, 7, 14, 28};

// ---- workspace layout (byte offsets). Packed weights in MFMA B-fragment order.
#define OFF_P0H 0UL
#define OFF_P0L (OFF_P0H + 2097152UL)   // cell0 pack: 128 ntile * 16 kb * 512 u16
#define OFF_P1H (OFF_P0L + 2097152UL)   // cell1 pack hi: 128 * 32 * 512 u16
#define OFF_P1L (OFF_P1H + 4194304UL)
#define OFF_H1H (OFF_P1L + 4194304UL)   // [2 parity][512*512] u16
#define OFF_H1L (OFF_H1H + 1048576UL)
#define OFF_H2H (OFF_H1L + 1048576UL)
#define OFF_H2L (OFF_H2H + 1048576UL)
#define OFF_H2F (OFF_H2L + 1048576UL)   // [2][512*512] f32
#define OFF_XF  (OFF_H2F + 2097152UL)   // encoder features [168][512][10] f32
#define OFF_SC  (OFF_XF  + 3440640UL)
#define OFF_LS  (OFF_SC  + 2048UL)
#define OFF_VAL (OFF_LS  + 2048UL)      // scaled series vals [512][52] f32
#define OFF_BAR (OFF_VAL + 106496UL)    // grid barrier flags: u32[256]
#define WS_NEED (OFF_BAR + 1024UL)
#define HPAR 262144UL                   // elements per parity plane

__device__ __forceinline__ float sigm(float x){ return 1.f / (1.f + __expf(-x)); }
__device__ __forceinline__ float tanhx(float x){
  float ax = fabsf(x);
  float t  = __expf(-2.f * ax);
  float r  = (1.f - t) / (1.f + t);
  return copysignf(r, x);
}
__device__ __forceinline__ u16 f2bf(float x){
  u32 u = __float_as_uint(x);
  return (u16)((u + 0x7FFFu + ((u >> 16) & 1u)) >> 16);  // RNE
}
__device__ __forceinline__ float bf2f(u16 h){ return __uint_as_float(((u32)h) << 16); }

// Grid barrier v3: per-block flag array — ZERO same-address RMWs.
// R7 post-mortem: 256 same-line fetch_adds serialize at the coherence point
// (~150ns each ~ 38us/phase) + 255 pollers hammering one generation line.
// Now: block w RMWs its OWN slot flags[w] (RELEASE, agent — RMW-at-coherence-
// point visibility is the R7-proven mechanism; 16 cachelines in parallel).
// Detection: 256 threads poll one flag each (coalesced 1KB), __syncthreads_or
// exit — self-throttled, no hot line. One acquire fence at exit (R5 lesson:
// acquire-per-poll = L2-invalidation storm).
// Hang-proof: monotone counters (stale read => extra spin only) + bounded
// rounds (~4ms/barrier cap) => structural failure = wrong answer, never hang.
__device__ __forceinline__ void gridbar(u32* flags, u32 target, int w){
  __syncthreads();
  if (threadIdx.x == 0)
    __hip_atomic_fetch_add(flags + w, 1u, __ATOMIC_RELEASE, __HIP_MEMORY_SCOPE_AGENT);
  u32 sp = 0;
  for (;;){
    u32 f = __hip_atomic_load(flags + threadIdx.x, __ATOMIC_RELAXED, __HIP_MEMORY_SCOPE_AGENT);
    if (!__syncthreads_or((int)(f < target))) break;
    if (++sp > 4000u) break;            // bounded: wrong answer, never a hang
    __builtin_amdgcn_s_sleep(2);
  }
  if (threadIdx.x == 0)
    __builtin_amdgcn_fence(__ATOMIC_ACQUIRE, "agent");
  __syncthreads();
}

// Gate GEMM tile, MF=2 (wave covers 32 rows x 64 gate-cols), K=32*KB, 3-term bf16 split.
// B-hi from LDS (bh_s), B-lo from bl_s (LDS for cell0, global for cell1).
// A (h state) from global parity planes; KB=32 splits A across h1 (kb<16) and h2 (kb>=16).
template<int KB>
__device__ __forceinline__ void cell_mfma2(
    const u16* __restrict__ AhiA, const u16* __restrict__ AloA,
    const u16* __restrict__ AhiB, const u16* __restrict__ AloB,
    const u16* bh_s, const u16* bl_s,
    int R0, float4 bias4, f32x4 (&acc)[2][4])
{
  const int lane = threadIdx.x & 63;
  const int lrow = lane & 15;
  {
    const float* bp = (const float*)&bias4;
    #pragma unroll
    for (int nf = 0; nf < 4; nf++){
      float bv = bp[nf];
      f32x4 v = {bv, bv, bv, bv};
      acc[0][nf] = v; acc[1][nf] = v;
    }
  }
  const size_t alo = (size_t)(lane >> 4) * 8;
  const u32 bo0 = (u32)lane * 8;
  #pragma unroll 4
  for (int kb = 0; kb < KB; kb++){
    const u16* Ah; const u16* Al; int kl;
    if (KB == 16 || kb < 16){ Ah = AhiA; Al = AloA; kl = kb; }
    else                     { Ah = AhiB; Al = AloB; kl = kb - 16; }
    bf16x8 ah[2], al[2];
    #pragma unroll
    for (int mf = 0; mf < 2; mf++){
      size_t ao = (size_t)(R0 + mf * 16 + lrow) * 512 + (size_t)kl * 32 + alo;
      ah[mf] = *(const bf16x8*)(Ah + ao);
      al[mf] = *(const bf16x8*)(Al + ao);
    }
    bf16x8 bh[4], bl[4];
    #pragma unroll
    for (int nf = 0; nf < 4; nf++){
      u32 off = ((u32)(nf * KB + kb) << 9) + bo0;
      bh[nf] = *(const bf16x8*)(bh_s + off);
      bl[nf] = *(const bf16x8*)(bl_s + off);
    }
    #pragma unroll
    for (int mf = 0; mf < 2; mf++){
      #pragma unroll
      for (int nf = 0; nf < 4; nf++){
        acc[mf][nf] = __builtin_amdgcn_mfma_f32_16x16x32_bf16(ah[mf], bh[nf], acc[mf][nf], 0, 0, 0);
        acc[mf][nf] = __builtin_amdgcn_mfma_f32_16x16x32_bf16(ah[mf], bl[nf], acc[mf][nf], 0, 0, 0);
        acc[mf][nf] = __builtin_amdgcn_mfma_f32_16x16x32_bf16(al[mf], bh[nf], acc[mf][nf], 0, 0, 0);
      }
    }
  }
}

// pointwise LSTM update; c-state held in registers across all 191 steps.
template<bool XP>
__device__ __forceinline__ void cell_epi2(
    f32x4 (&acc)[2][4], float (&creg)[8], int wrowbase, int m0, int jt,
    const float* xSl, const float* WihSl,
    u16* __restrict__ hhd, u16* __restrict__ hld, float* __restrict__ hfd)
{
  const int lane = threadIdx.x & 63;
  const int lrow = lane & 15, lkb = lane >> 4;
  const int j = jt * 16 + lrow;
  #pragma unroll
  for (int mf = 0; mf < 2; mf++){
    #pragma unroll
    for (int r = 0; r < 4; r++){
      int lr = wrowbase + mf * 16 + lkb * 4 + r;
      int b  = m0 + lr;
      float gi = acc[mf][0][r], gf = acc[mf][1][r], gg = acc[mf][2][r], go = acc[mf][3][r];
      if (XP){
        #pragma unroll
        for (int k = 0; k < 10; k++){
          float xv = xSl[lr * 10 + k];
          gi += xv * WihSl[(0 * 16 + lrow) * 10 + k];
          gf += xv * WihSl[(1 * 16 + lrow) * 10 + k];
          gg += xv * WihSl[(2 * 16 + lrow) * 10 + k];
          go += xv * WihSl[(3 * 16 + lrow) * 10 + k];
        }
      }
      float co = creg[mf * 4 + r];
      float cn = sigm(gf) * co + sigm(gi) * tanhx(gg);
      float h  = sigm(go) * tanhx(cn);
      creg[mf * 4 + r] = cn;
      size_t ci = ((size_t)b << 9) + j;
      u16 hh = f2bf(h);
      hhd[ci] = hh;
      hld[ci] = f2bf(h - bf2f(hh));
      if (hfd) hfd[ci] = h;
    }
  }
}

__global__ void initbar(unsigned char* ws){
  ((u32*)(ws + OFF_BAR))[threadIdx.x] = 0;
}

__global__ __launch_bounds__(256, 1) void deepar(
    const float* __restrict__ X,    const float* __restrict__ Wih0,
    const float* __restrict__ Whh0, const float* __restrict__ b0,
    const float* __restrict__ Wih1, const float* __restrict__ Whh1,
    const float* __restrict__ b1,   const float* __restrict__ Whead,
    const float* __restrict__ bhead, float* __restrict__ out,
    unsigned char* ws)
{
  __shared__ u16   BW[65536];     // 128 KB weight slice (cell0: hi+lo; cell1: hi)
  __shared__ float xS[1280];      // x features [128 rows][10]
  __shared__ float WihS[640];     // W_ih0 slice [64 gate-cols][10]
  __shared__ float WhS[512];      // W_head
  __shared__ float ylds[128];
  __shared__ float redS[4];

  u16*  p0h = (u16*)(ws + OFF_P0H);
  u16*  p0l = (u16*)(ws + OFF_P0L);
  u16*  p1h = (u16*)(ws + OFF_P1H);
  u16*  p1l = (u16*)(ws + OFF_P1L);
  u16*  h1h = (u16*)(ws + OFF_H1H);
  u16*  h1l = (u16*)(ws + OFF_H1L);
  u16*  h2h = (u16*)(ws + OFF_H2H);
  u16*  h2l = (u16*)(ws + OFF_H2L);
  float* h2f = (float*)(ws + OFF_H2F);
  float* xf  = (float*)(ws + OFF_XF);
  float* scp = (float*)(ws + OFF_SC);
  float* lsp = (float*)(ws + OFF_LS);
  float* valp = (float*)(ws + OFF_VAL);
  u32*  bar = (u32*)(ws + OFF_BAR);

  const int tid  = threadIdx.x;
  const int w    = blockIdx.x;
  const int wave = tid >> 6;
  const int jt   = w & 31;
  const int m0   = ((w >> 5) & 3) * 128;
  const int G    = 65536;
  const int gtid = w * 256 + tid;
  u32 bcnt = 0;

  float creg[8];
  #pragma unroll
  for (int i = 0; i < 8; i++) creg[i] = 0.f;

  // preload bias (this block's 64 gate-cols) and head bias into registers
  float4 bias4;
  {
    const float* bb = (w < 128) ? b0 : b1;
    int c = jt * 16 + (tid & 15);
    bias4.x = bb[0 * 512 + c]; bias4.y = bb[1 * 512 + c];
    bias4.z = bb[2 * 512 + c]; bias4.w = bb[3 * 512 + c];
  }
  const float bheadv = bhead[0];

  // ================= prep-A: zero state, per-series scale, weight packing =================
  for (int i = gtid; i < 524288; i += G){ h1h[i] = 0; h1l[i] = 0; h2h[i] = 0; h2l[i] = 0; h2f[i] = 0.f; }
  {
    int rowb = w * 2 + (tid >> 7);
    int t0 = tid & 127;
    float a = fabsf(X[((size_t)rowb * NL + 28 + t0) * 3]);
    if (t0 < 40) a += fabsf(X[((size_t)rowb * NL + 156 + t0) * 3]);
    #pragma unroll
    for (int off = 1; off < 64; off <<= 1) a += __shfl_xor(a, off, 64);
    if ((tid & 63) == 0) redS[tid >> 6] = a;
    __syncthreads();
    if (tid == 0 || tid == 128){
      float s = redS[tid >> 6] + redS[(tid >> 6) + 1];
      float sc = fmaxf(s / 168.f, 0.001f);
      scp[rowb] = sc; lsp[rowb] = logf(sc);
    }
  }
  // pack cell0 B (W_hh0)
  for (int idx = gtid; idx < 1048576; idx += G){
    int e = idx & 7, ln = (idx >> 3) & 63, kb = (idx >> 9) & 15, nt = idx >> 13;
    int n = (nt & 3) * 512 + (nt >> 2) * 16 + (ln & 15);
    int k = kb * 32 + (ln >> 4) * 8 + e;
    float wv = Whh0[(size_t)n * 512 + k];
    u16 hh = f2bf(wv);
    p0h[idx] = hh; p0l[idx] = f2bf(wv - bf2f(hh));
  }
  // pack cell1 B ([W_ih1 ; W_hh1], K=1024)
  for (int idx = gtid; idx < 2097152; idx += G){
    int e = idx & 7, ln = (idx >> 3) & 63, kb = (idx >> 9) & 31, nt = idx >> 14;
    int n = (nt & 3) * 512 + (nt >> 2) * 16 + (ln & 15);
    int k = kb * 32 + (ln >> 4) * 8 + e;
    float wv = (k < 512) ? Wih1[(size_t)n * 512 + k] : Whh1[(size_t)n * 512 + (k - 512)];
    u16 hh = f2bf(wv);
    p1h[idx] = hh; p1l[idx] = f2bf(wv - bf2f(hh));
  }
  gridbar(bar, ++bcnt, w);

  // ================= prep-B: features, valp, LDS residents =================
  for (int idx = gtid; idx < 860160; idx += G){
    int k = idx % 10; int r = idx / 10; int b = r & 511; int t = r >> 9;
    size_t xb = (size_t)b * NL;
    float v;
    if (k == 0)      v = X[(xb + 28 + t) * 3] / scp[b];
    else if (k < 3)  v = X[(xb + 28 + t) * 3 + k];
    else if (k == 3) v = lsp[b];
    else { int lag = LAGS[k - 4]; v = X[(xb + 28 + t - lag) * 3] / scp[b]; }
    xf[idx] = v;
  }
  for (int idx = gtid; idx < 512 * 28; idx += G){
    int b = idx / 28, v = idx % 28;
    valp[b * 52 + v] = X[((size_t)b * NL + 168 + v) * 3] / scp[b];
  }
  // stage this block's weight slice into LDS (written by prep-A, after barrier)
  if (w < 128){
    const uint4* sh = (const uint4*)(p0h + (size_t)jt * 32768);
    const uint4* sl = (const uint4*)(p0l + (size_t)jt * 32768);
    uint4* dB = (uint4*)BW;
    for (int i = tid; i < 4096; i += 256){ dB[i] = sh[i]; dB[4096 + i] = sl[i]; }
    for (int i = tid; i < 640; i += 256){
      int col = i / 10, k = i % 10;
      int n = (col >> 4) * 512 + jt * 16 + (col & 15);
      WihS[i] = Wih0[n * 10 + k];
    }
    for (int i = tid; i < 512; i += 256) WhS[i] = Whead[i];
  } else {
    const uint4* sh = (const uint4*)(p1h + (size_t)jt * 65536);
    uint4* dB = (uint4*)BW;
    for (int i = tid; i < 8192; i += 256) dB[i] = sh[i];
  }
  gridbar(bar, ++bcnt, w);

  // ================= encoder: pipelined, 1 barrier/phase =================
  // phase p: blocks 0-127 cell0(t=p); blocks 128-255 cell1(t=p-1); head y(t=p-2).
  for (int p = 0; p <= 168; p++){
    const int P = p & 1;
    if (w < 128){
      if ((w & 31) == 0 && p >= 2){
        int t = p - 2;
        int row = tid >> 1, q = tid & 1;
        int b = m0 + row;
        const float4* h4 = (const float4*)(h2f + (size_t)P * HPAR + ((size_t)b << 9) + q * 256);
        const float4* w4 = (const float4*)(WhS + q * 256);
        float s = 0.f;
        #pragma unroll 8
        for (int i = 0; i < 64; i++){ float4 a = h4[i], bw = w4[i]; s += a.x*bw.x + a.y*bw.y + a.z*bw.z + a.w*bw.w; }
        s += __shfl_xor(s, 1, 64);
        if (q == 0) out[(size_t)b * NOUT + t] = (s + bheadv) * scp[b];
      }
      if (p <= 167){
        for (int i = tid; i < 1280; i += 256) xS[i] = xf[(size_t)(p * 512 + m0) * 10 + i];
        __syncthreads();
        f32x4 acc[2][4];
        cell_mfma2<16>(h1h + (size_t)(1 - P) * HPAR, h1l + (size_t)(1 - P) * HPAR, nullptr, nullptr,
                       BW, BW + 32768, m0 + wave * 32, bias4, acc);
        cell_epi2<true>(acc, creg, wave * 32, m0, jt, xS, WihS,
                        h1h + (size_t)P * HPAR, h1l + (size_t)P * HPAR, nullptr);
      }
    } else {
      if (p >= 1){
        f32x4 acc[2][4];
        cell_mfma2<32>(h1h + (size_t)(1 - P) * HPAR, h1l + (size_t)(1 - P) * HPAR,
                       h2h + (size_t)P * HPAR,       h2l + (size_t)P * HPAR,
                       BW, p1l + (size_t)jt * 65536, m0 + wave * 32, bias4, acc);
        cell_epi2<false>(acc, creg, wave * 32, m0, jt, nullptr, nullptr,
                         h2h + (size_t)(1 - P) * HPAR, h2l + (size_t)(1 - P) * HPAR,
                         h2f + (size_t)(1 - P) * HPAR);
      }
    }
    gridbar(bar, ++bcnt, w);
  }

  // ================= decoder: 2 barriers/step =================
  for (int d = 0; d <= 22; d++){
    const int hp = (d + 1) & 1;     // parity of last h1/h2/h2f write
    if (w < 128){
      { // head y (output col 167+d); every cell0 block computes its own 128 rows
        int row = tid >> 1, q = tid & 1;
        int b = m0 + row;
        const float4* h4 = (const float4*)(h2f + (size_t)hp * HPAR + ((size_t)b << 9) + q * 256);
        const float4* w4 = (const float4*)(WhS + q * 256);
        float s = 0.f;
        #pragma unroll 8
        for (int i = 0; i < 64; i++){ float4 a = h4[i], bw = w4[i]; s += a.x*bw.x + a.y*bw.y + a.z*bw.z + a.w*bw.w; }
        s += __shfl_xor(s, 1, 64);
        if (q == 0){
          float y = s + bheadv;
          ylds[row] = y;
          if (jt == 0){
            out[(size_t)b * NOUT + 167 + d] = y * scp[b];
            valp[b * 52 + 28 + d] = y;
          }
        }
      }
      __syncthreads();
      if (tid < 128){
        int b = m0 + tid;
        size_t xb = (size_t)b * NL;
        float* xr = xS + tid * 10;
        xr[0] = ylds[tid];
        xr[1] = X[(xb + 196 + d) * 3 + 1];
        xr[2] = X[(xb + 196 + d) * 3 + 2];
        xr[3] = lsp[b];
        #pragma unroll
        for (int j2 = 0; j2 < 6; j2++) xr[4 + j2] = valp[b * 52 + 28 + d - LAGS[j2]];
      }
      __syncthreads();
      f32x4 acc[2][4];
      cell_mfma2<16>(h1h + (size_t)hp * HPAR, h1l + (size_t)hp * HPAR, nullptr, nullptr,
                     BW, BW + 32768, m0 + wave * 32, bias4, acc);
      cell_epi2<true>(acc, creg, wave * 32, m0, jt, xS, WihS,
                      h1h + (size_t)(d & 1) * HPAR, h1l + (size_t)(d & 1) * HPAR, nullptr);
    }
    gridbar(bar, ++bcnt, w);
    if (w >= 128){
      f32x4 acc[2][4];
      cell_mfma2<32>(h1h + (size_t)(d & 1) * HPAR, h1l + (size_t)(d & 1) * HPAR,
                     h2h + (size_t)hp * HPAR,      h2l + (size_t)hp * HPAR,
                     BW, p1l + (size_t)jt * 65536, m0 + wave * 32, bias4, acc);
      cell_epi2<false>(acc, creg, wave * 32, m0, jt, nullptr, nullptr,
                       h2h + (size_t)(d & 1) * HPAR, h2l + (size_t)(d & 1) * HPAR,
                       h2f + (size_t)(d & 1) * HPAR);
    }
    gridbar(bar, ++bcnt, w);
  }

  // final head: decoder step 23 output -> col 190 (h2f parity (22&1)=0)
  if (w < 128){
    int row = tid >> 1, q = tid & 1;
    int b = m0 + row;
    const float4* h4 = (const float4*)(h2f + ((size_t)b << 9) + q * 256);
    const float4* w4 = (const float4*)(WhS + q * 256);
    float s = 0.f;
    #pragma unroll 8
    for (int i = 0; i < 64; i++){ float4 a = h4[i], bw = w4[i]; s += a.x*bw.x + a.y*bw.y + a.z*bw.z + a.w*bw.w; }
    s += __shfl_xor(s, 1, 64);
    if (q == 0 && jt == 0) out[(size_t)b * NOUT + 190] = (s + bheadv) * scp[b];
  }
}

extern "C" void kernel_launch(void* const* d_in, const int* in_sizes, int n_in,
                              void* d_out, int out_size, void* d_ws, size_t ws_size,
                              hipStream_t stream) {
  (void)in_sizes; (void)n_in; (void)out_size;
  if (ws_size < WS_NEED) return;  // fail loudly (absmax) rather than corrupt
  const float* X    = (const float*)d_in[0];
  const float* Wih0 = (const float*)d_in[4];
  const float* Whh0 = (const float*)d_in[5];
  const float* b0   = (const float*)d_in[6];
  const float* Wih1 = (const float*)d_in[7];
  const float* Whh1 = (const float*)d_in[8];
  const float* b1   = (const float*)d_in[9];
  const float* Wh   = (const float*)d_in[10];
  const float* bh   = (const float*)d_in[11];
  float* out = (float*)d_out;
  unsigned char* ws = (unsigned char*)d_ws;

  initbar<<<dim3(1), dim3(256), 0, stream>>>(ws);
  deepar<<<dim3(256), dim3(256), 0, stream>>>(X, Wih0, Whh0, b0, Wih1, Whh1, b1, Wh, bh, out, ws);
}